// Round 2
// baseline (8051.228 us; speedup 1.0000x reference)
//
#include <hip/hip_runtime.h>
#include <math.h>

#define BATCH 8
#define T_STEPS 20
#define VOCAB 22
#define EDIM 64
#define HDIM 512
#define START_TOK 20

#define KC 4

typedef __attribute__((address_space(1))) const void* as1cv;
typedef __attribute__((address_space(3))) void* as3v;

__device__ __forceinline__ void gload_lds4(const float* g, float* l) {
    __builtin_amdgcn_global_load_lds((as1cv)g, (as3v)l, 4, 0, 0);
}
__device__ __forceinline__ void gload_lds16(const float* g, float* l) {
    __builtin_amdgcn_global_load_lds((as1cv)g, (as3v)l, 16, 0, 0);
}

// ---------------- weight transpose: w[Cout][Cin][9] -> wt[Cin][9][Cout] ----
__global__ __launch_bounds__(256) void transpose_w_kernel(
    const float* __restrict__ w, float* __restrict__ wt, int Cin, int Cout)
{
    size_t total = (size_t)Cout * Cin * 9;
    size_t idx = (size_t)blockIdx.x * 256 + threadIdx.x;
    if (idx >= total) return;
    int o = (int)(idx % Cout);
    size_t rest = idx / Cout;
    int tap = (int)(rest % 9);
    int ic = (int)(rest / 9);
    wt[idx] = w[((size_t)o * Cin + ic) * 9 + tap];
}

// ---------------- register-tiled conv 3x3 SAME (+relu if ks==1) -----------
// per-thread tile: 4 rows x 4 cols x 4 outs. block: (4*TYG rows) x (4*TXG cols) x 64 outs
// TYG*TXG == 16, 256 threads. Cin staged in chunks of KC=4.
// 2-phase async pipeline: global_load_lds DMA into double-buffered LDS;
// STAGE(k+1) is issued BEFORE compute(k) so HBM/L2 latency hides under FMAs.
// OOB halo lanes redirect their *global* address to a zeroed page (SAME padding).
template<int TYG, int TXG>
__global__ __launch_bounds__(256, 4) void conv_reg_kernel(
    const float* __restrict__ x, const float* __restrict__ wt,
    const float* __restrict__ bias, float* __restrict__ y,
    const float* __restrict__ zpage,
    int Cin, int Cout, int H, int W, int tiles_c, int ks, int cper)
{
    constexpr int TR = 4 * TYG;
    constexpr int TC = 4 * TXG;
    constexpr int XR = TR + 2;
    constexpr int XC = TC + 2;
    constexpr int XN = KC * XR * XC;          // X floats per chunk
    constexpr int XIT = (XN + 255) / 256;
    constexpr int WROWS = KC * 9;             // 36
    constexpr int WQ = WROWS * 16;            // x4-loads per chunk (64 floats/row)
    constexpr int WIT = (WQ + 255) / 256;

    __shared__ float xs[2][XN];
    __shared__ float wsh[2][WROWS * 64];

    int tile = blockIdx.x;
    int tr = tile / tiles_c, tc = tile - tr * tiles_c;
    int r0 = tr * TR, c0 = tc * TC;
    int nb = blockIdx.z;          // = n*ks + ksi
    int ksi = nb % ks;
    int n = nb / ks;
    int ob = blockIdx.y * 64;
    int tid = threadIdx.x;
    int tx = tid % TXG;                       // col group
    int ty = (tid / TXG) % TYG;               // row group
    int tz = tid >> 4;                        // o group (4 outs)
    int wid = tid >> 6;                       // wave id (LDS dst must be wave-uniform)

    // ---- precompute per-iteration global offsets + validity (chunk-invariant)
    int xoff[XIT];
    unsigned xvalid = 0;
    #pragma unroll
    for (int it = 0; it < XIT; ++it) {
        int idx = it * 256 + tid;
        int i = idx / (XR * XC);
        int rem = idx - i * (XR * XC);
        int lr = rem / XC;
        int lc = rem - lr * XC;
        int gr = r0 - 1 + lr, gc = c0 - 1 + lc;
        bool v = (idx < XN) && ((unsigned)gr < (unsigned)H) && ((unsigned)gc < (unsigned)W);
        xoff[it] = (i * H + gr) * W + gc;
        if (v) xvalid |= (1u << it);
    }
    int woff[WIT];
    #pragma unroll
    for (int it = 0; it < WIT; ++it) {
        int idx = it * 256 + tid;
        int row = idx >> 4;                   // i*9 + tap
        int o4 = (idx & 15) * 4;
        woff[it] = row * Cout + ob + o4;
    }

    const float* xn_ = x + (size_t)n * Cin * H * W;
    int ic_beg = ksi * cper;
    int nch = cper / KC;

    auto stage = [&](int buf, int ic0) {
        const float* xc = xn_ + (size_t)ic0 * H * W;
        #pragma unroll
        for (int it = 0; it < XIT; ++it) {
            int idx = it * 256 + tid;
            if (idx < XN) {
                const float* src = ((xvalid >> it) & 1) ? (xc + xoff[it]) : zpage;
                gload_lds4(src, &xs[buf][it * 256 + wid * 64]);
            }
        }
        const float* wc = wt + (size_t)ic0 * 9 * Cout;
        #pragma unroll
        for (int it = 0; it < WIT; ++it) {
            int idx = it * 256 + tid;
            if (idx < WQ) {
                gload_lds16(wc + woff[it], &wsh[buf][(it * 256 + wid * 64) * 4]);
            }
        }
    };

    float acc[4][4][4];   // [r][c][o]
    #pragma unroll
    for (int r = 0; r < 4; ++r)
        #pragma unroll
        for (int c = 0; c < 4; ++c)
            #pragma unroll
            for (int j = 0; j < 4; ++j) acc[r][c][j] = 0.f;

    stage(0, ic_beg);
    __syncthreads();   // emits vmcnt(0) drain -> buf0 ready

    int cur = 0;
    for (int c = 0; c < nch; ++c) {
        if (c + 1 < nch) stage(cur ^ 1, ic_beg + (c + 1) * KC);   // issue-early
        const float* xb = &xs[cur][0];
        const float* wb = &wsh[cur][0];
        #pragma unroll 2
        for (int i = 0; i < KC; ++i) {
            float xv[6][6];
            #pragma unroll
            for (int rr = 0; rr < 6; ++rr) {
                #pragma unroll
                for (int jj = 0; jj < 3; ++jj) {
                    float2 t = *(const float2*)&xb[(i * XR + 4 * ty + rr) * XC + 4 * tx + 2 * jj];
                    xv[rr][2 * jj]     = t.x;
                    xv[rr][2 * jj + 1] = t.y;
                }
            }
            #pragma unroll
            for (int kh = 0; kh < 3; ++kh) {
                #pragma unroll
                for (int kw = 0; kw < 3; ++kw) {
                    float4 wv = *(const float4*)&wb[(i * 9 + kh * 3 + kw) * 64 + tz * 4];
                    #pragma unroll
                    for (int r = 0; r < 4; ++r) {
                        #pragma unroll
                        for (int cc = 0; cc < 4; ++cc) {
                            float xvv = xv[r + kh][cc + kw];
                            acc[r][cc][0] = fmaf(xvv, wv.x, acc[r][cc][0]);
                            acc[r][cc][1] = fmaf(xvv, wv.y, acc[r][cc][1]);
                            acc[r][cc][2] = fmaf(xvv, wv.z, acc[r][cc][2]);
                            acc[r][cc][3] = fmaf(xvv, wv.w, acc[r][cc][3]);
                        }
                    }
                }
            }
        }
        __syncthreads();   // waves done with buf cur; DMA into buf cur^1 drained
        cur ^= 1;
    }

    // epilogue
    int row0 = r0 + 4 * ty;
    int col0 = c0 + 4 * tx;
    if (col0 >= W) return;
    float4 bv = make_float4(0.f, 0.f, 0.f, 0.f);
    if (ks == 1) bv = *(const float4*)&bias[ob + tz * 4];
    bool full4 = (col0 + 3 < W);
    #pragma unroll
    for (int r = 0; r < 4; ++r) {
        int row = row0 + r;
        if (row >= H) continue;
        size_t rbase = (size_t)row * W + col0;
        #pragma unroll
        for (int j = 0; j < 4; ++j) {
            int o = ob + tz * 4 + j;
            float bj = (j == 0) ? bv.x : (j == 1) ? bv.y : (j == 2) ? bv.z : bv.w;
            float* yo = y + ((size_t)nb * Cout + o) * ((size_t)H * W) + rbase;
            float v0 = acc[r][0][j] + bj;
            float v1 = acc[r][1][j] + bj;
            float v2 = acc[r][2][j] + bj;
            float v3 = acc[r][3][j] + bj;
            if (ks == 1) {
                v0 = fmaxf(v0, 0.f); v1 = fmaxf(v1, 0.f);
                v2 = fmaxf(v2, 0.f); v3 = fmaxf(v3, 0.f);
            }
            if (full4 && ((rbase & 3) == 0)) {
                *(float4*)yo = make_float4(v0, v1, v2, v3);
            } else {
                yo[0] = v0;
                if (col0 + 1 < W) yo[1] = v1;
                if (col0 + 2 < W) yo[2] = v2;
                if (col0 + 3 < W) yo[3] = v3;
            }
        }
    }
}

// ---------------- reduce ks partials + bias + relu ------------------------
__global__ __launch_bounds__(256) void ksum_kernel(
    const float* __restrict__ part, const float* __restrict__ bias,
    float* __restrict__ y, int ks, int Cout, int HW)
{
    size_t total = (size_t)BATCH * Cout * HW;
    size_t i = (size_t)blockIdx.x * 256 + threadIdx.x;
    if (i >= total) return;
    int sp = (int)(i % HW);
    size_t r = i / HW;
    int o = (int)(r % Cout);
    int n = (int)(r / Cout);
    float s = 0.f;
    for (int k = 0; k < ks; ++k)
        s += part[(((size_t)(n * ks + k) * Cout + o) * HW) + sp];
    y[i] = fmaxf(s + bias[o], 0.f);
}

// ---------------- conv 3x3 SAME + relu (direct; layer 1 only, Cin=3) ------
__global__ __launch_bounds__(256) void conv3x3_relu_kernel(
    const float* __restrict__ x, const float* __restrict__ w,
    const float* __restrict__ bias, float* __restrict__ y,
    int Cin, int Cout, int Hs, int Ws)
{
    int HW = Hs * Ws;
    int sp = blockIdx.x * 256 + threadIdx.x;
    if (sp >= HW) return;
    int h = sp / Ws;
    int col = sp - h * Ws;
    int o = blockIdx.y;
    int n = blockIdx.z;
    const float* xn = x + (size_t)n * Cin * HW;
    const float* wo = w + (size_t)o * Cin * 9;
    float acc = bias[o];
    if (h >= 1 && h < Hs - 1 && col >= 1 && col < Ws - 1) {
        const float* xr = xn + (size_t)(h - 1) * Ws + (col - 1);
        for (int i = 0; i < Cin; ++i) {
            const float* xc = xr + (size_t)i * HW;
            const float* wc = wo + i * 9;
            acc += xc[0] * wc[0] + xc[1] * wc[1] + xc[2] * wc[2];
            acc += xc[Ws] * wc[3] + xc[Ws + 1] * wc[4] + xc[Ws + 2] * wc[5];
            acc += xc[2 * Ws] * wc[6] + xc[2 * Ws + 1] * wc[7] + xc[2 * Ws + 2] * wc[8];
        }
    } else {
        for (int i = 0; i < Cin; ++i) {
            const float* xc = xn + (size_t)i * HW;
            const float* wc = wo + i * 9;
            #pragma unroll
            for (int kh = 0; kh < 3; ++kh) {
                int hh = h + kh - 1;
                if (hh < 0 || hh >= Hs) continue;
                #pragma unroll
                for (int kw = 0; kw < 3; ++kw) {
                    int cc = col + kw - 1;
                    if (cc < 0 || cc >= Ws) continue;
                    acc += xc[hh * Ws + cc] * wc[kh * 3 + kw];
                }
            }
        }
    }
    y[((size_t)n * Cout + o) * HW + sp] = fmaxf(acc, 0.f);
}

// ---------------- 2x2 maxpool stride 2 ----------------
__global__ __launch_bounds__(256) void maxpool2_kernel(
    const float* __restrict__ x, float* __restrict__ y, int C, int Hin, int Win)
{
    int Ho = Hin >> 1, Wo = Win >> 1;
    size_t total = (size_t)BATCH * C * Ho * Wo;
    size_t i = (size_t)blockIdx.x * 256 + threadIdx.x;
    if (i >= total) return;
    int wo = (int)(i % Wo);
    size_t r = i / Wo;
    int ho = (int)(r % Ho);
    r /= Ho;  // r = n*C + c
    const float* xp = x + (r * Hin + 2 * (size_t)ho) * Win + 2 * wo;
    float m = fmaxf(fmaxf(xp[0], xp[1]), fmaxf(xp[Win], xp[Win + 1]));
    y[i] = m;
}

// ---------------- linear: Y[b][o] = act(sum_k X[b][k]*W[o][k] + bias[o]) ----
__global__ __launch_bounds__(256) void linear8_kernel(
    const float* __restrict__ X, const float* __restrict__ W,
    const float* __restrict__ bias, float* __restrict__ Y,
    int K, int O, int doRelu)
{
    int o = blockIdx.x;
    const float* wr = W + (size_t)o * K;
    float acc[BATCH];
    #pragma unroll
    for (int b = 0; b < BATCH; ++b) acc[b] = 0.f;
    for (int k = threadIdx.x; k < K; k += 256) {
        float wv = wr[k];
        #pragma unroll
        for (int b = 0; b < BATCH; ++b)
            acc[b] = fmaf(X[(size_t)b * K + k], wv, acc[b]);
    }
    __shared__ float red[4][BATCH];
    int lane = threadIdx.x & 63, wid = threadIdx.x >> 6;
    #pragma unroll
    for (int b = 0; b < BATCH; ++b) {
        float v = acc[b];
        #pragma unroll
        for (int off = 32; off > 0; off >>= 1) v += __shfl_down(v, off, 64);
        if (lane == 0) red[wid][b] = v;
    }
    __syncthreads();
    if (threadIdx.x < BATCH) {
        float v = red[0][threadIdx.x] + red[1][threadIdx.x] +
                  red[2][threadIdx.x] + red[3][threadIdx.x];
        v += bias[o];
        if (doRelu) v = fmaxf(v, 0.f);
        Y[(size_t)threadIdx.x * O + o] = v;
    }
}

// ---------------- zero init ----------------
__global__ __launch_bounds__(256) void zero_kernel(float* __restrict__ p, int n)
{
    int i = blockIdx.x * 256 + threadIdx.x;
    if (i < n) p[i] = 0.f;
}

// ---------------- one LSTM step ----------------
__global__ __launch_bounds__(256) void lstm_step_kernel(
    const float* __restrict__ embed_W, const int* __restrict__ tokens,
    const float* __restrict__ w_ih, const float* __restrict__ w_hh,
    const float* __restrict__ b_ih, const float* __restrict__ b_hh,
    const float* __restrict__ h_in, const float* __restrict__ c_in,
    float* __restrict__ h_out, float* __restrict__ c_out, int t)
{
    int idx = blockIdx.x * 256 + threadIdx.x;  // 0 .. B*HDIM-1
    int b = idx >> 9;
    int j = idx & (HDIM - 1);
    int tok = (t == 0) ? START_TOK : tokens[b * T_STEPS + (t - 1)];
    const float* e = embed_W + (size_t)tok * EDIM;
    const float* hb = h_in + (size_t)b * HDIM;
    float g[4];
    #pragma unroll
    for (int q = 0; q < 4; ++q) {
        int row = q * HDIM + j;
        float a = b_ih[row] + b_hh[row];
        const float* wi = w_ih + (size_t)row * EDIM;
        for (int k = 0; k < EDIM; ++k) a = fmaf(e[k], wi[k], a);
        const float* wh = w_hh + (size_t)row * HDIM;
        for (int k = 0; k < HDIM; ++k) a = fmaf(hb[k], wh[k], a);
        g[q] = a;
    }
    float ig = 1.f / (1.f + expf(-g[0]));
    float fg = 1.f / (1.f + expf(-g[1]));
    float gg = tanhf(g[2]);
    float og = 1.f / (1.f + expf(-g[3]));
    float c = fg * c_in[idx] + ig * gg;
    float h = og * tanhf(c);
    c_out[idx] = c;
    h_out[idx] = h;
}

// ---------------- decode: proj_rnn + relu + scores + log_softmax ----------
__global__ __launch_bounds__(64) void decode_kernel(
    const float* __restrict__ hs, const float* __restrict__ proj_rnn_w,
    const float* __restrict__ proj_rnn_b, const float* __restrict__ img_emb,
    const float* __restrict__ embed_W, float* __restrict__ out)
{
    int bid = blockIdx.x;        // t*B + b
    int t = bid >> 3;
    int b = bid & 7;
    int e = threadIdx.x;         // 0..63
    const float* hrow = hs + ((size_t)t * BATCH + b) * HDIM;
    float a = proj_rnn_b[e] + img_emb[b * EDIM + e];
    const float* wr = proj_rnn_w + (size_t)e * HDIM;
    for (int k = 0; k < HDIM; ++k) a = fmaf(hrow[k], wr[k], a);
    a = fmaxf(a, 0.f);
    __shared__ float xdec[EDIM];
    __shared__ float sc[VOCAB];
    xdec[e] = a;
    __syncthreads();
    if (e < VOCAB) {
        float s = 0.f;
        if (e == START_TOK) {
            for (int k = 0; k < EDIM; ++k) s += xdec[k];
            s *= -1e9f;
        } else {
            const float* w2 = embed_W + (size_t)e * EDIM;
            for (int k = 0; k < EDIM; ++k) s = fmaf(xdec[k], w2[k], s);
        }
        sc[e] = s;
    }
    __syncthreads();
    if (e == 0) {
        float m = -INFINITY;
        for (int v = 0; v < VOCAB; ++v) m = fmaxf(m, sc[v]);
        float sum = 0.f;
        for (int v = 0; v < VOCAB; ++v) sum += expf(sc[v] - m);
        float lse = m + logf(sum);
        for (int v = 0; v < VOCAB; ++v)
            out[((size_t)b * T_STEPS + t) * VOCAB + v] = sc[v] - lse;
    }
}

// ---------------- host launch ----------------
static const int CIN_[13]  = {3, 64, 64, 128, 128, 256, 256, 256, 512, 512, 512, 512, 512};
static const int COUT_[13] = {64, 64, 128, 128, 256, 256, 256, 512, 512, 512, 512, 512, 512};
static const int HSZ_[13]  = {224, 224, 112, 112, 56, 56, 56, 28, 28, 28, 14, 14, 14};
static const bool POOL_[13] = {false, true, false, true, false, false, true,
                               false, false, true, false, false, true};
// Cin-split factor per layer (deep small-spatial layers need more grid parallelism)
static const int KS_[13]   = {1, 1, 1, 1, 1, 1, 1, 2, 2, 2, 8, 8, 8};

extern "C" void kernel_launch(void* const* d_in, const int* in_sizes, int n_in,
                              void* d_out, int out_size, void* d_ws, size_t ws_size,
                              hipStream_t stream) {
    const float* fc1_w = (const float*)d_in[26];
    const float* fc1_b = (const float*)d_in[27];
    const float* fc2_w = (const float*)d_in[28];
    const float* fc2_b = (const float*)d_in[29];
    const float* embed_W = (const float*)d_in[30];
    const float* w_ih = (const float*)d_in[31];
    const float* w_hh = (const float*)d_in[32];
    const float* b_ih = (const float*)d_in[33];
    const float* b_hh = (const float*)d_in[34];
    const float* proj_rnn_w = (const float*)d_in[35];
    const float* proj_rnn_b = (const float*)d_in[36];
    const float* proj_img_w = (const float*)d_in[37];
    const float* proj_img_b = (const float*)d_in[38];
    const float* images = (const float*)d_in[39];
    const int* tokens = (const int*)d_in[40];
    float* out = (float*)d_out;

    char* p = (char*)d_ws;
    auto alloc = [&](size_t nbytes) -> float* {
        float* r = (float*)p;
        p += (nbytes + 255) & ~(size_t)255;
        return r;
    };
    const size_t MAXACT = (size_t)BATCH * 64 * 224 * 224;  // 25,690,112 floats
    float* bufs[2];
    bufs[0] = alloc(MAXACT * 4);
    bufs[1] = alloc(MAXACT * 4);
    float* f1 = alloc((size_t)BATCH * 4096 * 4);
    float* f2 = alloc((size_t)BATCH * 4096 * 4);
    float* img_emb = alloc((size_t)BATCH * EDIM * 4);
    float* zeros = alloc((size_t)BATCH * HDIM * 4);
    float* cbuf = alloc((size_t)BATCH * HDIM * 4);
    float* hs = alloc((size_t)T_STEPS * BATCH * HDIM * 4);
    float* wt = alloc((size_t)512 * 9 * 512 * 4);  // transposed weights (max 9.4MB)
    float* zpage = alloc(256);                      // zero page for halo OOB lanes

    zero_kernel<<<1, 256, 0, stream>>>(zpage, 64);

    // ---- VGG conv stack ----
    int di = 0;
    const float* cur = images;
    for (int i = 0; i < 13; ++i) {
        int Hs = HSZ_[i], Ws = Hs, HW = Hs * Ws;
        float* dst = bufs[di]; di ^= 1;
        if (i == 0) {
            dim3 grid((HW + 255) / 256, COUT_[i], BATCH);
            conv3x3_relu_kernel<<<grid, 256, 0, stream>>>(
                cur, (const float*)d_in[0], (const float*)d_in[1], dst,
                CIN_[i], COUT_[i], Hs, Ws);
        } else {
            size_t wtotal = (size_t)COUT_[i] * CIN_[i] * 9;
            transpose_w_kernel<<<(int)((wtotal + 255) / 256), 256, 0, stream>>>(
                (const float*)d_in[2 * i], wt, CIN_[i], COUT_[i]);
            int ks = KS_[i];
            int cper = CIN_[i] / ks;
            // ks>1: write raw partials into the tail of dst buffer (8M floats in,
            // partial size <= 6.5M floats, dst payload <= 3.3M floats -> no overlap)
            float* tgt = (ks == 1) ? dst : (dst + (size_t)8 * 1024 * 1024);
            if (Hs == 56) {
                int tiles_r = (Hs + 7) / 8, tiles_c = (Ws + 31) / 32;
                dim3 grid(tiles_r * tiles_c, COUT_[i] / 64, BATCH * ks);
                conv_reg_kernel<2, 8><<<grid, 256, 0, stream>>>(
                    cur, wt, (const float*)d_in[2 * i + 1], tgt, zpage,
                    CIN_[i], COUT_[i], Hs, Ws, tiles_c, ks, cper);
            } else {
                int tiles_r = (Hs + 15) / 16, tiles_c = (Ws + 15) / 16;
                dim3 grid(tiles_r * tiles_c, COUT_[i] / 64, BATCH * ks);
                conv_reg_kernel<4, 4><<<grid, 256, 0, stream>>>(
                    cur, wt, (const float*)d_in[2 * i + 1], tgt, zpage,
                    CIN_[i], COUT_[i], Hs, Ws, tiles_c, ks, cper);
            }
            if (ks > 1) {
                size_t total = (size_t)BATCH * COUT_[i] * HW;
                ksum_kernel<<<(int)((total + 255) / 256), 256, 0, stream>>>(
                    tgt, (const float*)d_in[2 * i + 1], dst, ks, COUT_[i], HW);
            }
        }
        cur = dst;
        if (POOL_[i]) {
            float* pdst = bufs[di]; di ^= 1;
            size_t total = (size_t)BATCH * COUT_[i] * (Hs / 2) * (Ws / 2);
            maxpool2_kernel<<<(int)((total + 255) / 256), 256, 0, stream>>>(
                cur, pdst, COUT_[i], Hs, Ws);
            cur = pdst;
        }
    }

    // ---- classifier ----
    linear8_kernel<<<4096, 256, 0, stream>>>(cur, fc1_w, fc1_b, f1, 25088, 4096, 1);
    linear8_kernel<<<4096, 256, 0, stream>>>(f1, fc2_w, fc2_b, f2, 4096, 4096, 1);
    linear8_kernel<<<64, 256, 0, stream>>>(f2, proj_img_w, proj_img_b, img_emb, 4096, 64, 0);

    // ---- LSTM ----
    zero_kernel<<<16, 256, 0, stream>>>(zeros, BATCH * HDIM);
    for (int t = 0; t < T_STEPS; ++t) {
        const float* h_in = (t == 0) ? zeros : (hs + (size_t)(t - 1) * BATCH * HDIM);
        const float* c_in = (t == 0) ? zeros : cbuf;
        lstm_step_kernel<<<16, 256, 0, stream>>>(
            embed_W, tokens, w_ih, w_hh, b_ih, b_hh,
            h_in, c_in, hs + (size_t)t * BATCH * HDIM, cbuf, t);
    }

    // ---- decode ----
    decode_kernel<<<T_STEPS * BATCH, 64, 0, stream>>>(
        hs, proj_rnn_w, proj_rnn_b, img_emb, embed_W, out);
}

// Round 3
// 6235.800 us; speedup vs baseline: 1.2911x; 1.2911x over previous
//
#include <hip/hip_runtime.h>
#include <math.h>

#define BATCH 8
#define T_STEPS 20
#define VOCAB 22
#define EDIM 64
#define HDIM 512
#define START_TOK 20

#define KC 4

// ---------------- weight transpose: w[Cout][Cin][9] -> wt[Cin][9][Cout] ----
__global__ __launch_bounds__(256) void transpose_w_kernel(
    const float* __restrict__ w, float* __restrict__ wt, int Cin, int Cout)
{
    size_t total = (size_t)Cout * Cin * 9;
    size_t idx = (size_t)blockIdx.x * 256 + threadIdx.x;
    if (idx >= total) return;
    int o = (int)(idx % Cout);
    size_t rest = idx / Cout;
    int tap = (int)(rest % 9);
    int ic = (int)(rest / 9);
    wt[idx] = w[((size_t)o * Cin + ic) * 9 + tap];
}

// ---------------- register-tiled conv 3x3 SAME (+relu if ks==1) -----------
// per-thread tile: 4 rows x 4 cols x 4 outs. block: (4*TYG rows) x (4*TXG cols) x 64 outs
// TYG*TXG == 16, 256 threads. Cin staged in chunks of KC=4.
// T14 pipeline (issue-early / write-late), double-buffered LDS:
//   { glob->reg loads for chunk c+1 | compute(buf cur) | reg->LDS writes to
//     buf cur^1 (vmcnt wait lands here, hidden by compute) | one barrier }.
template<int TYG, int TXG>
__global__ __launch_bounds__(256, 2) void conv_reg_kernel(
    const float* __restrict__ x, const float* __restrict__ wt,
    const float* __restrict__ bias, float* __restrict__ y,
    int Cin, int Cout, int H, int W, int tiles_c, int ks, int cper)
{
    constexpr int TR = 4 * TYG;
    constexpr int TC = 4 * TXG;
    constexpr int XR = TR + 2;
    constexpr int XC = TC + 2;
    constexpr int XN = KC * XR * XC;          // X floats per chunk
    constexpr int XIT = (XN + 255) / 256;
    constexpr int WROWS = KC * 9;             // 36
    constexpr int WN = WROWS * 64;            // W floats per chunk
    constexpr int WQ = WROWS * 16;            // float4 loads per chunk
    constexpr int WIT = (WQ + 255) / 256;

    __shared__ float xs_[2 * XN];
    __shared__ float ws_[2 * WN];

    int tile = blockIdx.x;
    int tr = tile / tiles_c, tc = tile - tr * tiles_c;
    int r0 = tr * TR, c0 = tc * TC;
    int nb = blockIdx.z;          // = n*ks + ksi
    int ksi = nb % ks;
    int n = nb / ks;
    int ob = blockIdx.y * 64;
    int tid = threadIdx.x;
    int tx = tid % TXG;                       // col group
    int ty = (tid / TXG) % TYG;               // row group
    int tz = tid >> 4;                        // o group (4 outs)

    // ---- chunk-invariant global offsets + validity ----
    int xoff[XIT];
    unsigned xvalid = 0;
    #pragma unroll
    for (int it = 0; it < XIT; ++it) {
        int idx = it * 256 + tid;
        int i = idx / (XR * XC);
        int rem = idx - i * (XR * XC);
        int lr = rem / XC;
        int lc = rem - lr * XC;
        int gr = r0 - 1 + lr, gc = c0 - 1 + lc;
        bool v = (idx < XN) && ((unsigned)gr < (unsigned)H) && ((unsigned)gc < (unsigned)W);
        xoff[it] = (i * H + gr) * W + gc;
        if (v) xvalid |= (1u << it);
    }
    int woff[WIT];
    unsigned wvalid = 0;
    #pragma unroll
    for (int it = 0; it < WIT; ++it) {
        int idx = it * 256 + tid;
        int row = idx >> 4;                   // i*9 + tap
        int o4 = (idx & 15) * 4;
        woff[it] = row * Cout + ob + o4;
        if (idx < WQ) wvalid |= (1u << it);
    }

    const float* xn_ = x + (size_t)n * Cin * H * W;
    int ic_beg = ksi * cper;
    int nch = cper / KC;

    float xr_[XIT];
    float4 wr_[WIT];

    auto gload = [&](int ic0) {
        const float* xc = xn_ + (size_t)ic0 * H * W;
        #pragma unroll
        for (int it = 0; it < XIT; ++it)
            xr_[it] = ((xvalid >> it) & 1) ? xc[xoff[it]] : 0.f;
        const float* wc = wt + (size_t)ic0 * 9 * Cout;
        #pragma unroll
        for (int it = 0; it < WIT; ++it)
            wr_[it] = ((wvalid >> it) & 1) ? *(const float4*)(wc + woff[it])
                                           : make_float4(0.f, 0.f, 0.f, 0.f);
    };
    auto push = [&](float* xw, float* ww) {
        #pragma unroll
        for (int it = 0; it < XIT; ++it) {
            int idx = it * 256 + tid;
            if (idx < XN) xw[idx] = xr_[it];
        }
        #pragma unroll
        for (int it = 0; it < WIT; ++it) {
            int idx = it * 256 + tid;
            if (idx < WQ) *(float4*)&ww[idx * 4] = wr_[it];
        }
    };

    float acc[4][4][4];   // [r][c][o]
    #pragma unroll
    for (int r = 0; r < 4; ++r)
        #pragma unroll
        for (int c = 0; c < 4; ++c)
            #pragma unroll
            for (int j = 0; j < 4; ++j) acc[r][c][j] = 0.f;

    gload(ic_beg);
    push(xs_, ws_);
    __syncthreads();

    int cur = 0;
    for (int c = 0; c < nch; ++c) {
        if (c + 1 < nch) gload(ic_beg + (c + 1) * KC);   // issue-early
        const float* xb = xs_ + cur * XN;
        const float* wb = ws_ + cur * WN;
        #pragma unroll 2
        for (int i = 0; i < KC; ++i) {
            float xv[6][6];
            #pragma unroll
            for (int rr = 0; rr < 6; ++rr) {
                #pragma unroll
                for (int jj = 0; jj < 3; ++jj) {
                    float2 t = *(const float2*)&xb[(i * XR + 4 * ty + rr) * XC + 4 * tx + 2 * jj];
                    xv[rr][2 * jj]     = t.x;
                    xv[rr][2 * jj + 1] = t.y;
                }
            }
            #pragma unroll
            for (int kh = 0; kh < 3; ++kh) {
                #pragma unroll
                for (int kw = 0; kw < 3; ++kw) {
                    float4 wv = *(const float4*)&wb[(i * 9 + kh * 3 + kw) * 64 + tz * 4];
                    #pragma unroll
                    for (int r = 0; r < 4; ++r) {
                        #pragma unroll
                        for (int cc = 0; cc < 4; ++cc) {
                            float xvv = xv[r + kh][cc + kw];
                            acc[r][cc][0] = fmaf(xvv, wv.x, acc[r][cc][0]);
                            acc[r][cc][1] = fmaf(xvv, wv.y, acc[r][cc][1]);
                            acc[r][cc][2] = fmaf(xvv, wv.z, acc[r][cc][2]);
                            acc[r][cc][3] = fmaf(xvv, wv.w, acc[r][cc][3]);
                        }
                    }
                }
            }
        }
        if (c + 1 < nch) push(xs_ + (cur ^ 1) * XN, ws_ + (cur ^ 1) * WN);  // write-late
        __syncthreads();
        cur ^= 1;
    }

    // epilogue
    int row0 = r0 + 4 * ty;
    int col0 = c0 + 4 * tx;
    if (col0 >= W) return;
    float4 bv = make_float4(0.f, 0.f, 0.f, 0.f);
    if (ks == 1) bv = *(const float4*)&bias[ob + tz * 4];
    bool full4 = (col0 + 3 < W);
    #pragma unroll
    for (int r = 0; r < 4; ++r) {
        int row = row0 + r;
        if (row >= H) continue;
        size_t rbase = (size_t)row * W + col0;
        #pragma unroll
        for (int j = 0; j < 4; ++j) {
            int o = ob + tz * 4 + j;
            float bj = (j == 0) ? bv.x : (j == 1) ? bv.y : (j == 2) ? bv.z : bv.w;
            float* yo = y + ((size_t)nb * Cout + o) * ((size_t)H * W) + rbase;
            float v0 = acc[r][0][j] + bj;
            float v1 = acc[r][1][j] + bj;
            float v2 = acc[r][2][j] + bj;
            float v3 = acc[r][3][j] + bj;
            if (ks == 1) {
                v0 = fmaxf(v0, 0.f); v1 = fmaxf(v1, 0.f);
                v2 = fmaxf(v2, 0.f); v3 = fmaxf(v3, 0.f);
            }
            if (full4 && ((rbase & 3) == 0)) {
                *(float4*)yo = make_float4(v0, v1, v2, v3);
            } else {
                yo[0] = v0;
                if (col0 + 1 < W) yo[1] = v1;
                if (col0 + 2 < W) yo[2] = v2;
                if (col0 + 3 < W) yo[3] = v3;
            }
        }
    }
}

// ---------------- reduce ks partials + bias + relu ------------------------
__global__ __launch_bounds__(256) void ksum_kernel(
    const float* __restrict__ part, const float* __restrict__ bias,
    float* __restrict__ y, int ks, int Cout, int HW)
{
    size_t total = (size_t)BATCH * Cout * HW;
    size_t i = (size_t)blockIdx.x * 256 + threadIdx.x;
    if (i >= total) return;
    int sp = (int)(i % HW);
    size_t r = i / HW;
    int o = (int)(r % Cout);
    int n = (int)(r / Cout);
    float s = 0.f;
    for (int k = 0; k < ks; ++k)
        s += part[(((size_t)(n * ks + k) * Cout + o) * HW) + sp];
    y[i] = fmaxf(s + bias[o], 0.f);
}

// ---------------- conv 3x3 SAME + relu (direct; layer 1 only, Cin=3) ------
__global__ __launch_bounds__(256) void conv3x3_relu_kernel(
    const float* __restrict__ x, const float* __restrict__ w,
    const float* __restrict__ bias, float* __restrict__ y,
    int Cin, int Cout, int Hs, int Ws)
{
    int HW = Hs * Ws;
    int sp = blockIdx.x * 256 + threadIdx.x;
    if (sp >= HW) return;
    int h = sp / Ws;
    int col = sp - h * Ws;
    int o = blockIdx.y;
    int n = blockIdx.z;
    const float* xn = x + (size_t)n * Cin * HW;
    const float* wo = w + (size_t)o * Cin * 9;
    float acc = bias[o];
    if (h >= 1 && h < Hs - 1 && col >= 1 && col < Ws - 1) {
        const float* xr = xn + (size_t)(h - 1) * Ws + (col - 1);
        for (int i = 0; i < Cin; ++i) {
            const float* xc = xr + (size_t)i * HW;
            const float* wc = wo + i * 9;
            acc += xc[0] * wc[0] + xc[1] * wc[1] + xc[2] * wc[2];
            acc += xc[Ws] * wc[3] + xc[Ws + 1] * wc[4] + xc[Ws + 2] * wc[5];
            acc += xc[2 * Ws] * wc[6] + xc[2 * Ws + 1] * wc[7] + xc[2 * Ws + 2] * wc[8];
        }
    } else {
        for (int i = 0; i < Cin; ++i) {
            const float* xc = xn + (size_t)i * HW;
            const float* wc = wo + i * 9;
            #pragma unroll
            for (int kh = 0; kh < 3; ++kh) {
                int hh = h + kh - 1;
                if (hh < 0 || hh >= Hs) continue;
                #pragma unroll
                for (int kw = 0; kw < 3; ++kw) {
                    int cc = col + kw - 1;
                    if (cc < 0 || cc >= Ws) continue;
                    acc += xc[hh * Ws + cc] * wc[kh * 3 + kw];
                }
            }
        }
    }
    y[((size_t)n * Cout + o) * HW + sp] = fmaxf(acc, 0.f);
}

// ---------------- 2x2 maxpool stride 2 ----------------
__global__ __launch_bounds__(256) void maxpool2_kernel(
    const float* __restrict__ x, float* __restrict__ y, int C, int Hin, int Win)
{
    int Ho = Hin >> 1, Wo = Win >> 1;
    size_t total = (size_t)BATCH * C * Ho * Wo;
    size_t i = (size_t)blockIdx.x * 256 + threadIdx.x;
    if (i >= total) return;
    int wo = (int)(i % Wo);
    size_t r = i / Wo;
    int ho = (int)(r % Ho);
    r /= Ho;  // r = n*C + c
    const float* xp = x + (r * Hin + 2 * (size_t)ho) * Win + 2 * wo;
    float m = fmaxf(fmaxf(xp[0], xp[1]), fmaxf(xp[Win], xp[Win + 1]));
    y[i] = m;
}

// ---------------- linear: Y[b][o] = act(sum_k X[b][k]*W[o][k] + bias[o]) ----
__global__ __launch_bounds__(256) void linear8_kernel(
    const float* __restrict__ X, const float* __restrict__ W,
    const float* __restrict__ bias, float* __restrict__ Y,
    int K, int O, int doRelu)
{
    int o = blockIdx.x;
    const float* wr = W + (size_t)o * K;
    float acc[BATCH];
    #pragma unroll
    for (int b = 0; b < BATCH; ++b) acc[b] = 0.f;
    for (int k = threadIdx.x; k < K; k += 256) {
        float wv = wr[k];
        #pragma unroll
        for (int b = 0; b < BATCH; ++b)
            acc[b] = fmaf(X[(size_t)b * K + k], wv, acc[b]);
    }
    __shared__ float red[4][BATCH];
    int lane = threadIdx.x & 63, wid = threadIdx.x >> 6;
    #pragma unroll
    for (int b = 0; b < BATCH; ++b) {
        float v = acc[b];
        #pragma unroll
        for (int off = 32; off > 0; off >>= 1) v += __shfl_down(v, off, 64);
        if (lane == 0) red[wid][b] = v;
    }
    __syncthreads();
    if (threadIdx.x < BATCH) {
        float v = red[0][threadIdx.x] + red[1][threadIdx.x] +
                  red[2][threadIdx.x] + red[3][threadIdx.x];
        v += bias[o];
        if (doRelu) v = fmaxf(v, 0.f);
        Y[(size_t)threadIdx.x * O + o] = v;
    }
}

// ---------------- zero init ----------------
__global__ __launch_bounds__(256) void zero_kernel(float* __restrict__ p, int n)
{
    int i = blockIdx.x * 256 + threadIdx.x;
    if (i < n) p[i] = 0.f;
}

// ---------------- one LSTM step ----------------
__global__ __launch_bounds__(256) void lstm_step_kernel(
    const float* __restrict__ embed_W, const int* __restrict__ tokens,
    const float* __restrict__ w_ih, const float* __restrict__ w_hh,
    const float* __restrict__ b_ih, const float* __restrict__ b_hh,
    const float* __restrict__ h_in, const float* __restrict__ c_in,
    float* __restrict__ h_out, float* __restrict__ c_out, int t)
{
    int idx = blockIdx.x * 256 + threadIdx.x;  // 0 .. B*HDIM-1
    int b = idx >> 9;
    int j = idx & (HDIM - 1);
    int tok = (t == 0) ? START_TOK : tokens[b * T_STEPS + (t - 1)];
    const float* e = embed_W + (size_t)tok * EDIM;
    const float* hb = h_in + (size_t)b * HDIM;
    float g[4];
    #pragma unroll
    for (int q = 0; q < 4; ++q) {
        int row = q * HDIM + j;
        float a = b_ih[row] + b_hh[row];
        const float* wi = w_ih + (size_t)row * EDIM;
        for (int k = 0; k < EDIM; ++k) a = fmaf(e[k], wi[k], a);
        const float* wh = w_hh + (size_t)row * HDIM;
        for (int k = 0; k < HDIM; ++k) a = fmaf(hb[k], wh[k], a);
        g[q] = a;
    }
    float ig = 1.f / (1.f + expf(-g[0]));
    float fg = 1.f / (1.f + expf(-g[1]));
    float gg = tanhf(g[2]);
    float og = 1.f / (1.f + expf(-g[3]));
    float c = fg * c_in[idx] + ig * gg;
    float h = og * tanhf(c);
    c_out[idx] = c;
    h_out[idx] = h;
}

// ---------------- decode: proj_rnn + relu + scores + log_softmax ----------
__global__ __launch_bounds__(64) void decode_kernel(
    const float* __restrict__ hs, const float* __restrict__ proj_rnn_w,
    const float* __restrict__ proj_rnn_b, const float* __restrict__ img_emb,
    const float* __restrict__ embed_W, float* __restrict__ out)
{
    int bid = blockIdx.x;        // t*B + b
    int t = bid >> 3;
    int b = bid & 7;
    int e = threadIdx.x;         // 0..63
    const float* hrow = hs + ((size_t)t * BATCH + b) * HDIM;
    float a = proj_rnn_b[e] + img_emb[b * EDIM + e];
    const float* wr = proj_rnn_w + (size_t)e * HDIM;
    for (int k = 0; k < HDIM; ++k) a = fmaf(hrow[k], wr[k], a);
    a = fmaxf(a, 0.f);
    __shared__ float xdec[EDIM];
    __shared__ float sc[VOCAB];
    xdec[e] = a;
    __syncthreads();
    if (e < VOCAB) {
        float s = 0.f;
        if (e == START_TOK) {
            for (int k = 0; k < EDIM; ++k) s += xdec[k];
            s *= -1e9f;
        } else {
            const float* w2 = embed_W + (size_t)e * EDIM;
            for (int k = 0; k < EDIM; ++k) s = fmaf(xdec[k], w2[k], s);
        }
        sc[e] = s;
    }
    __syncthreads();
    if (e == 0) {
        float m = -INFINITY;
        for (int v = 0; v < VOCAB; ++v) m = fmaxf(m, sc[v]);
        float sum = 0.f;
        for (int v = 0; v < VOCAB; ++v) sum += expf(sc[v] - m);
        float lse = m + logf(sum);
        for (int v = 0; v < VOCAB; ++v)
            out[((size_t)b * T_STEPS + t) * VOCAB + v] = sc[v] - lse;
    }
}

// ---------------- host launch ----------------
static const int CIN_[13]  = {3, 64, 64, 128, 128, 256, 256, 256, 512, 512, 512, 512, 512};
static const int COUT_[13] = {64, 64, 128, 128, 256, 256, 256, 512, 512, 512, 512, 512, 512};
static const int HSZ_[13]  = {224, 224, 112, 112, 56, 56, 56, 28, 28, 28, 14, 14, 14};
static const bool POOL_[13] = {false, true, false, true, false, false, true,
                               false, false, true, false, false, true};
// Cin-split factor per layer: small-spatial layers need more grid parallelism
// (56^2: 448->896 blocks; 28^2: 256->1024; 14^2: 64->512)
static const int KS_[13]   = {1, 1, 1, 1, 2, 2, 2, 4, 4, 4, 8, 8, 8};

extern "C" void kernel_launch(void* const* d_in, const int* in_sizes, int n_in,
                              void* d_out, int out_size, void* d_ws, size_t ws_size,
                              hipStream_t stream) {
    const float* fc1_w = (const float*)d_in[26];
    const float* fc1_b = (const float*)d_in[27];
    const float* fc2_w = (const float*)d_in[28];
    const float* fc2_b = (const float*)d_in[29];
    const float* embed_W = (const float*)d_in[30];
    const float* w_ih = (const float*)d_in[31];
    const float* w_hh = (const float*)d_in[32];
    const float* b_ih = (const float*)d_in[33];
    const float* b_hh = (const float*)d_in[34];
    const float* proj_rnn_w = (const float*)d_in[35];
    const float* proj_rnn_b = (const float*)d_in[36];
    const float* proj_img_w = (const float*)d_in[37];
    const float* proj_img_b = (const float*)d_in[38];
    const float* images = (const float*)d_in[39];
    const int* tokens = (const int*)d_in[40];
    float* out = (float*)d_out;

    char* p = (char*)d_ws;
    auto alloc = [&](size_t nbytes) -> float* {
        float* r = (float*)p;
        p += (nbytes + 255) & ~(size_t)255;
        return r;
    };
    const size_t MAXACT = (size_t)BATCH * 64 * 224 * 224;  // 25,690,112 floats
    float* bufs[2];
    bufs[0] = alloc(MAXACT * 4);
    bufs[1] = alloc(MAXACT * 4);
    float* f1 = alloc((size_t)BATCH * 4096 * 4);
    float* f2 = alloc((size_t)BATCH * 4096 * 4);
    float* img_emb = alloc((size_t)BATCH * EDIM * 4);
    float* zeros = alloc((size_t)BATCH * HDIM * 4);
    float* cbuf = alloc((size_t)BATCH * HDIM * 4);
    float* hs = alloc((size_t)T_STEPS * BATCH * HDIM * 4);
    float* wt = alloc((size_t)512 * 9 * 512 * 4);  // transposed weights (max 9.4MB)

    // ---- VGG conv stack ----
    int di = 0;
    const float* cur = images;
    for (int i = 0; i < 13; ++i) {
        int Hs = HSZ_[i], Ws = Hs, HW = Hs * Ws;
        float* dst = bufs[di]; di ^= 1;
        if (i == 0) {
            dim3 grid((HW + 255) / 256, COUT_[i], BATCH);
            conv3x3_relu_kernel<<<grid, 256, 0, stream>>>(
                cur, (const float*)d_in[0], (const float*)d_in[1], dst,
                CIN_[i], COUT_[i], Hs, Ws);
        } else {
            size_t wtotal = (size_t)COUT_[i] * CIN_[i] * 9;
            transpose_w_kernel<<<(int)((wtotal + 255) / 256), 256, 0, stream>>>(
                (const float*)d_in[2 * i], wt, CIN_[i], COUT_[i]);
            int ks = KS_[i];
            int cper = CIN_[i] / ks;
            // ks>1: raw partials in the tail of dst buffer (partial <= 12.9M floats
            // at offset 8M; payload <= 6.4M floats; MAXACT = 25.69M -> no overlap)
            float* tgt = (ks == 1) ? dst : (dst + (size_t)8 * 1024 * 1024);
            if (Hs == 56) {
                int tiles_r = (Hs + 7) / 8, tiles_c = (Ws + 31) / 32;
                dim3 grid(tiles_r * tiles_c, COUT_[i] / 64, BATCH * ks);
                conv_reg_kernel<2, 8><<<grid, 256, 0, stream>>>(
                    cur, wt, (const float*)d_in[2 * i + 1], tgt,
                    CIN_[i], COUT_[i], Hs, Ws, tiles_c, ks, cper);
            } else {
                int tiles_r = (Hs + 15) / 16, tiles_c = (Ws + 15) / 16;
                dim3 grid(tiles_r * tiles_c, COUT_[i] / 64, BATCH * ks);
                conv_reg_kernel<4, 4><<<grid, 256, 0, stream>>>(
                    cur, wt, (const float*)d_in[2 * i + 1], tgt,
                    CIN_[i], COUT_[i], Hs, Ws, tiles_c, ks, cper);
            }
            if (ks > 1) {
                size_t total = (size_t)BATCH * COUT_[i] * HW;
                ksum_kernel<<<(int)((total + 255) / 256), 256, 0, stream>>>(
                    tgt, (const float*)d_in[2 * i + 1], dst, ks, COUT_[i], HW);
            }
        }
        cur = dst;
        if (POOL_[i]) {
            float* pdst = bufs[di]; di ^= 1;
            size_t total = (size_t)BATCH * COUT_[i] * (Hs / 2) * (Ws / 2);
            maxpool2_kernel<<<(int)((total + 255) / 256), 256, 0, stream>>>(
                cur, pdst, COUT_[i], Hs, Ws);
            cur = pdst;
        }
    }

    // ---- classifier ----
    linear8_kernel<<<4096, 256, 0, stream>>>(cur, fc1_w, fc1_b, f1, 25088, 4096, 1);
    linear8_kernel<<<4096, 256, 0, stream>>>(f1, fc2_w, fc2_b, f2, 4096, 4096, 1);
    linear8_kernel<<<64, 256, 0, stream>>>(f2, proj_img_w, proj_img_b, img_emb, 4096, 64, 0);

    // ---- LSTM ----
    zero_kernel<<<16, 256, 0, stream>>>(zeros, BATCH * HDIM);
    for (int t = 0; t < T_STEPS; ++t) {
        const float* h_in = (t == 0) ? zeros : (hs + (size_t)(t - 1) * BATCH * HDIM);
        const float* c_in = (t == 0) ? zeros : cbuf;
        lstm_step_kernel<<<16, 256, 0, stream>>>(
            embed_W, tokens, w_ih, w_hh, b_ih, b_hh,
            h_in, c_in, hs + (size_t)t * BATCH * HDIM, cbuf, t);
    }

    // ---- decode ----
    decode_kernel<<<T_STEPS * BATCH, 64, 0, stream>>>(
        hs, proj_rnn_w, proj_rnn_b, img_emb, embed_W, out);
}